// Round 1
// baseline (577.886 us; speedup 1.0000x reference)
//
#include <hip/hip_runtime.h>

#define NN 4096
#define ALPHA 0.2f
#define FLTMAX 3.402823466e+38f

__device__ __forceinline__ float lrelu(float x) { return x > 0.f ? x : ALPHA * x; }

// ---------------- k1: Wh = h @ W.T + b, src/dst = einsum(Wh, a) ----------------
#define K1R 16
__global__ __launch_bounds__(256) void k1_gemm(
    const float* __restrict__ hin, const float* __restrict__ W,
    const float* __restrict__ bias, const float* __restrict__ av,
    float* __restrict__ Wh, float* __restrict__ srcv, float* __restrict__ dstv)
{
  __shared__ __align__(16) float hs[K1R * 256];   // 16 KB
  __shared__ __align__(16) float wts[32 * 256];   // 32 KB (W chunk, transposed)
  const int t = threadIdx.x;
  const int r0 = blockIdx.x * K1R;

  {
    const float4* h4 = (const float4*)(hin + (size_t)r0 * 256);
    float4* hs4 = (float4*)hs;
#pragma unroll
    for (int i = 0; i < K1R * 64 / 256; ++i) hs4[i * 256 + t] = h4[i * 256 + t];
  }

  float acc[K1R];
#pragma unroll
  for (int r = 0; r < K1R; ++r) acc[r] = 0.f;

  for (int k0 = 0; k0 < 256; k0 += 32) {
    __syncthreads();  // first iter: hs ready; later: previous compute done
    {
      const float4* wrow = (const float4*)(W + (size_t)t * 256 + k0);
#pragma unroll
      for (int q = 0; q < 8; ++q) {
        float4 v = wrow[q];
        wts[(4 * q + 0) * 256 + t] = v.x;
        wts[(4 * q + 1) * 256 + t] = v.y;
        wts[(4 * q + 2) * 256 + t] = v.z;
        wts[(4 * q + 3) * 256 + t] = v.w;
      }
    }
    __syncthreads();
    float wreg[32];
#pragma unroll
    for (int kk = 0; kk < 32; ++kk) wreg[kk] = wts[kk * 256 + t];
#pragma unroll
    for (int r = 0; r < K1R; ++r) {
      const float4* hrow = (const float4*)(hs + r * 256 + k0);
      float s = acc[r];
#pragma unroll
      for (int q = 0; q < 8; ++q) {
        float4 hv = hrow[q];
        s += hv.x * wreg[4*q+0] + hv.y * wreg[4*q+1] + hv.z * wreg[4*q+2] + hv.w * wreg[4*q+3];
      }
      acc[r] = s;
    }
  }

  const int hh = t >> 6, lane = t & 63;
  const float asrc = av[hh * 128 + lane];
  const float adst = av[hh * 128 + 64 + lane];
  const float bc = bias[t];
#pragma unroll
  for (int r = 0; r < K1R; ++r) {
    float w = acc[r] + bc;
    Wh[(size_t)(r0 + r) * 256 + t] = w;
    float s = w * asrc, d = w * adst;
#pragma unroll
    for (int off = 32; off >= 1; off >>= 1) {
      s += __shfl_xor(s, off);
      d += __shfl_xor(d, off);
    }
    if (lane == 0) {
      srcv[(size_t)(r0 + r) * 4 + hh] = s;
      dstv[(size_t)(r0 + r) * 4 + hh] = d;
    }
  }
}

// ---------------- k2: adj -> bitmask, masked max of dst per row ----------------
__global__ __launch_bounds__(256) void k2_mask(
    const int* __restrict__ adj, const float* __restrict__ dstv,
    unsigned long long* __restrict__ bmask, float* __restrict__ mdstv)
{
  __shared__ __align__(16) float dstl[4 * NN];   // SoA per head: 64 KB, conflict-free reads
  __shared__ float4 redm[8 * 4];
  const int t = threadIdx.x;
#pragma unroll
  for (int i = 0; i < 16; ++i) {
    int j = i * 256 + t;
    float4 v = ((const float4*)dstv)[j];
    dstl[0 * NN + j] = v.x;
    dstl[1 * NN + j] = v.y;
    dstl[2 * NN + j] = v.z;
    dstl[3 * NN + j] = v.w;
  }
  __syncthreads();

  const int i0 = blockIdx.x * 8;
  const int wid = t >> 6, lane = t & 63;
  for (int r = 0; r < 8; ++r) {
    const size_t row = (size_t)(i0 + r);
    const int* arow = adj + row * NN;
    float mx = -FLTMAX, my = -FLTMAX, mz = -FLTMAX, mw = -FLTMAX;
#pragma unroll
    for (int it = 0; it < 16; ++it) {
      int j = it * 256 + t;
      bool pred = (arow[j] == 1);
      unsigned long long bal = __ballot(pred);
      mx = fmaxf(mx, pred ? dstl[0 * NN + j] : -FLTMAX);
      my = fmaxf(my, pred ? dstl[1 * NN + j] : -FLTMAX);
      mz = fmaxf(mz, pred ? dstl[2 * NN + j] : -FLTMAX);
      mw = fmaxf(mw, pred ? dstl[3 * NN + j] : -FLTMAX);
      if (lane == 0) bmask[row * 64 + it * 4 + wid] = bal;
    }
#pragma unroll
    for (int off = 32; off >= 1; off >>= 1) {
      mx = fmaxf(mx, __shfl_xor(mx, off));
      my = fmaxf(my, __shfl_xor(my, off));
      mz = fmaxf(mz, __shfl_xor(mz, off));
      mw = fmaxf(mw, __shfl_xor(mw, off));
    }
    if (lane == 0) redm[r * 4 + wid] = make_float4(mx, my, mz, mw);
  }
  __syncthreads();
  if (t < 8) {
    float4 a0 = redm[t*4+0], a1 = redm[t*4+1], a2 = redm[t*4+2], a3 = redm[t*4+3];
    float4 mm;
    mm.x = fmaxf(fmaxf(a0.x, a1.x), fmaxf(a2.x, a3.x));
    mm.y = fmaxf(fmaxf(a0.y, a1.y), fmaxf(a2.y, a3.y));
    mm.z = fmaxf(fmaxf(a0.z, a1.z), fmaxf(a2.z, a3.z));
    mm.w = fmaxf(fmaxf(a0.w, a1.w), fmaxf(a2.w, a3.w));
    *(float4*)(mdstv + (size_t)(i0 + t) * 4) = mm;
  }
}

// ---------------- k3: masked softmax + PV (partial over j-split) ----------------
// grid = 128 rowblocks (TI=32 rows) x 4 j-splits (1024 j each) = 512 blocks
#define TI 32
#define PLH 2056  // 64*32 + 8 pad (bank spread across heads)
__global__ __launch_bounds__(256, 2) void k3_pv(
    const float* __restrict__ Wh, const float* __restrict__ srcv,
    const float* __restrict__ dstv, const float* __restrict__ mdstv,
    const unsigned long long* __restrict__ bmask,
    float* __restrict__ pacc, float* __restrict__ pden)
{
  __shared__ unsigned long long msk[TI][17];          // pad 17: avoid bank clash
  __shared__ __align__(16) float Pl[4 * PLH];          // P tile [h][jj][r], ~33 KB
  __shared__ __align__(16) float dsts[64 * 4];         // dst tile, AoS
  __shared__ float srcl[TI * 4], ml[TI * 4];
  __shared__ int uni[TI];
  __shared__ float pdenl[256];
  __shared__ float denl[TI * 4];

  const int t = threadIdx.x;
  const int rb = blockIdx.x & 127, s = blockIdx.x >> 7;
  const int i0 = rb * TI;
  const int w0 = s * 16;   // 64-bit word offset within a row's mask

  for (int i = t; i < TI * 16; i += 256) {
    int r = i >> 4, w = i & 15;
    msk[r][w] = bmask[(size_t)(i0 + r) * 64 + w0 + w];
  }
  if (t < TI) {
    float4 sv = *(const float4*)(srcv + (size_t)(i0 + t) * 4);
    float4 mv = *(const float4*)(mdstv + (size_t)(i0 + t) * 4);
    uni[t] = (mv.x == -FLTMAX) ? 1 : 0;
    srcl[t*4+0] = sv.x; srcl[t*4+1] = sv.y; srcl[t*4+2] = sv.z; srcl[t*4+3] = sv.w;
    ml[t*4+0] = lrelu(sv.x + mv.x);
    ml[t*4+1] = lrelu(sv.y + mv.y);
    ml[t*4+2] = lrelu(sv.z + mv.z);
    ml[t*4+3] = lrelu(sv.w + mv.w);
  }

  float acc[TI];
#pragma unroll
  for (int r = 0; r < TI; ++r) acc[r] = 0.f;
  float dacc = 0.f;

  const int hw = t >> 6;                         // PV: wave = head
  const int r_p = t & 31, h_p = (t >> 5) & 3, q_p = t >> 7;  // P-compute role

  for (int tile = 0; tile < 16; ++tile) {
    const int j0 = s * 1024 + tile * 64;
    __syncthreads();   // previous PV done before overwriting dsts/Pl
    if (t < 64) *(float4*)(dsts + t * 4) = *(const float4*)(dstv + (size_t)(j0 + t) * 4);
    __syncthreads();
    {
      const float sr = srcl[r_p * 4 + h_p];
      const float mr = ml[r_p * 4 + h_p];
      const unsigned int w32 = (unsigned int)(msk[r_p][tile] >> (q_p * 32));
      const int u = uni[r_p];
      float* pl = Pl + h_p * PLH + r_p;
#pragma unroll
      for (int i2 = 0; i2 < 32; ++i2) {
        const int jj = q_p * 32 + i2;
        float dv = dsts[jj * 4 + h_p];
        float e = lrelu(sr + dv);
        float p = ((w32 >> i2) & 1u) ? __expf(e - mr) : 0.f;
        if (u) p = 1.f;
        pl[jj * 32] = p;
        dacc += p;
      }
    }
    __syncthreads();
    {
      const float* whp = Wh + (size_t)j0 * 256 + t;
      const float* plr = Pl + hw * PLH;
#pragma unroll 4
      for (int jj = 0; jj < 64; ++jj) {
        float wv = whp[(size_t)jj * 256];
        const float* pb = plr + jj * 32;
#pragma unroll
        for (int rq = 0; rq < 8; ++rq) {
          float4 p4 = *(const float4*)(pb + rq * 4);
          acc[rq*4+0] += p4.x * wv;
          acc[rq*4+1] += p4.y * wv;
          acc[rq*4+2] += p4.z * wv;
          acc[rq*4+3] += p4.w * wv;
        }
      }
    }
  }

  pdenl[q_p * 128 + r_p * 4 + h_p] = dacc;
  __syncthreads();
  if (t < 128) denl[t] = pdenl[t] + pdenl[128 + t];
  __syncthreads();
  {
    float* pa = pacc + ((size_t)(s * NN) + i0) * 256 + t;
#pragma unroll
    for (int r = 0; r < TI; ++r) pa[(size_t)r * 256] = acc[r];
    if (t < 128) pden[((size_t)(s * NN) + i0) * 4 + t] = denl[t];
  }
}

// ---------------- k4: combine partials, divide ----------------
__global__ __launch_bounds__(256) void k4_combine(
    const float* __restrict__ pacc, const float* __restrict__ pden,
    float* __restrict__ out)
{
  const int i = blockIdx.x, c = threadIdx.x, h = c >> 6;
  float num = 0.f, den = 0.f;
#pragma unroll
  for (int s = 0; s < 4; ++s) {
    num += pacc[((size_t)(s * NN + i)) * 256 + c];
    den += pden[(size_t)(s * NN + i) * 4 + h];
  }
  out[(size_t)i * 256 + c] = num / den;
}

extern "C" void kernel_launch(void* const* d_in, const int* in_sizes, int n_in,
                              void* d_out, int out_size, void* d_ws, size_t ws_size,
                              hipStream_t stream) {
  const float* hin  = (const float*)d_in[0];
  const int*   adj  = (const int*)d_in[1];
  const float* W    = (const float*)d_in[2];
  const float* bias = (const float*)d_in[3];
  const float* av   = (const float*)d_in[4];
  float* out = (float*)d_out;

  char* ws = (char*)d_ws;
  float* Wh    = (float*)ws;                                  // 4 MB
  float* srcv  = (float*)(ws + (4u << 20));                   // 64 KB
  float* dstv  = srcv + NN * 4;                               // 64 KB
  float* mdstv = dstv + NN * 4;                               // 64 KB
  unsigned long long* bmask = (unsigned long long*)(ws + (4u << 20) + 196608); // 2 MB
  float* pacc  = (float*)(ws + (4u << 20) + 196608 + (2u << 20));              // 16 MB
  float* pden  = pacc + (size_t)4 * NN * 256;                                  // 256 KB

  k1_gemm<<<NN / K1R, 256, 0, stream>>>(hin, W, bias, av, Wh, srcv, dstv);
  k2_mask<<<NN / 8, 256, 0, stream>>>(adj, dstv, bmask, mdstv);
  k3_pv<<<512, 256, 0, stream>>>(Wh, srcv, dstv, mdstv, bmask, pacc, pden);
  k4_combine<<<NN, 256, 0, stream>>>(pacc, pden, out);
}

// Round 3
// 259.722 us; speedup vs baseline: 2.2250x; 2.2250x over previous
//
#include <hip/hip_runtime.h>

#define NN 4096
#define ALPHA 0.2f
#define FLTMAX 3.402823466e+38f

typedef __attribute__((ext_vector_type(8))) short short8x;
typedef __attribute__((ext_vector_type(4))) float f32x4;
typedef unsigned long long u64;

__device__ __forceinline__ float lrelu(float x) { return x > 0.f ? x : ALPHA * x; }

// round-to-nearest-even f32 -> bf16 bits
__device__ __forceinline__ unsigned short f2bf(float f) {
  unsigned u = __float_as_uint(f);
  u += 0x7fffu + ((u >> 16) & 1u);
  return (unsigned short)(u >> 16);
}
__device__ __forceinline__ float bf2f(unsigned short s) {
  return __uint_as_float(((unsigned)s) << 16);
}

// ---------------- k1: Wh = h @ W.T + b; WhT bf16 [256][4096]; src/dst ----------------
#define K1R 8
__global__ __launch_bounds__(256) void k1_gemm(
    const float* __restrict__ hin, const float* __restrict__ W,
    const float* __restrict__ bias, const float* __restrict__ av,
    unsigned short* __restrict__ WhT, float* __restrict__ srcv,
    float* __restrict__ dstv_soa)
{
  __shared__ __align__(16) float hs[K1R * 256];   // 8 KB
  __shared__ __align__(16) float wts[32 * 256];   // 32 KB
  const int t = threadIdx.x;
  const int r0 = blockIdx.x * K1R;

  {
    const float4* h4 = (const float4*)(hin + (size_t)r0 * 256);
    float4* hs4 = (float4*)hs;
#pragma unroll
    for (int i = 0; i < K1R * 64 / 256; ++i) hs4[i * 256 + t] = h4[i * 256 + t];
  }

  float acc[K1R];
#pragma unroll
  for (int r = 0; r < K1R; ++r) acc[r] = 0.f;

  for (int k0 = 0; k0 < 256; k0 += 32) {
    __syncthreads();
    {
      const float4* wrow = (const float4*)(W + (size_t)t * 256 + k0);
#pragma unroll
      for (int q = 0; q < 8; ++q) {
        float4 v = wrow[q];
        wts[(4 * q + 0) * 256 + t] = v.x;
        wts[(4 * q + 1) * 256 + t] = v.y;
        wts[(4 * q + 2) * 256 + t] = v.z;
        wts[(4 * q + 3) * 256 + t] = v.w;
      }
    }
    __syncthreads();
    float wreg[32];
#pragma unroll
    for (int kk = 0; kk < 32; ++kk) wreg[kk] = wts[kk * 256 + t];
#pragma unroll
    for (int r = 0; r < K1R; ++r) {
      const float4* hrow = (const float4*)(hs + r * 256 + k0);
      float s = acc[r];
#pragma unroll
      for (int q = 0; q < 8; ++q) {
        float4 hv = hrow[q];
        s += hv.x * wreg[4*q+0] + hv.y * wreg[4*q+1] + hv.z * wreg[4*q+2] + hv.w * wreg[4*q+3];
      }
      acc[r] = s;
    }
  }

  const int hh = t >> 6, lane = t & 63;
  const float asrc = av[hh * 128 + lane];
  const float adst = av[hh * 128 + 64 + lane];
  const float bc = bias[t];
  unsigned short wb[K1R];
#pragma unroll
  for (int r = 0; r < K1R; ++r) {
    float w = acc[r] + bc;
    wb[r] = f2bf(w);
    float s = w * asrc, d = w * adst;
#pragma unroll
    for (int off = 32; off >= 1; off >>= 1) {
      s += __shfl_xor(s, off);
      d += __shfl_xor(d, off);
    }
    if (lane == 0) {
      srcv[(size_t)(r0 + r) * 4 + hh] = s;
      dstv_soa[(size_t)hh * NN + r0 + r] = d;
    }
  }
  // thread t holds column t for rows r0..r0+7 -> transposed store is contiguous
  {
    short8x v;
#pragma unroll
    for (int r = 0; r < K1R; ++r) v[r] = (short)wb[r];
    *(short8x*)(WhT + (size_t)t * NN + r0) = v;
  }
}

// ---------------- k2: adj -> bitmask, masked max of dst per row ----------------
__global__ __launch_bounds__(256) void k2_mask(
    const int* __restrict__ adj, const float* __restrict__ dstv_soa,
    u64* __restrict__ bmask, float* __restrict__ mdstv)
{
  __shared__ __align__(16) float dstl[4 * NN];   // 64 KB SoA
  __shared__ float4 redm[8 * 4];
  const int t = threadIdx.x;
#pragma unroll
  for (int i = 0; i < 16; ++i) {
    int j4 = i * 256 + t;
    ((float4*)dstl)[j4] = ((const float4*)dstv_soa)[j4];
  }
  __syncthreads();

  const int i0 = blockIdx.x * 8;
  const int wid = t >> 6, lane = t & 63;
  for (int r = 0; r < 8; ++r) {
    const size_t row = (size_t)(i0 + r);
    const int* arow = adj + row * NN;
    float mx = -FLTMAX, my = -FLTMAX, mz = -FLTMAX, mw = -FLTMAX;
#pragma unroll
    for (int it = 0; it < 16; ++it) {
      int j = it * 256 + t;
      bool pred = (arow[j] == 1);
      u64 bal = __ballot(pred);
      mx = fmaxf(mx, pred ? dstl[0 * NN + j] : -FLTMAX);
      my = fmaxf(my, pred ? dstl[1 * NN + j] : -FLTMAX);
      mz = fmaxf(mz, pred ? dstl[2 * NN + j] : -FLTMAX);
      mw = fmaxf(mw, pred ? dstl[3 * NN + j] : -FLTMAX);
      if (lane == 0) bmask[row * 64 + it * 4 + wid] = bal;
    }
#pragma unroll
    for (int off = 32; off >= 1; off >>= 1) {
      mx = fmaxf(mx, __shfl_xor(mx, off));
      my = fmaxf(my, __shfl_xor(my, off));
      mz = fmaxf(mz, __shfl_xor(mz, off));
      mw = fmaxf(mw, __shfl_xor(mw, off));
    }
    if (lane == 0) redm[r * 4 + wid] = make_float4(mx, my, mz, mw);
  }
  __syncthreads();
  if (t < 8) {
    float4 a0 = redm[t*4+0], a1 = redm[t*4+1], a2 = redm[t*4+2], a3 = redm[t*4+3];
    float4 mm;
    mm.x = fmaxf(fmaxf(a0.x, a1.x), fmaxf(a2.x, a3.x));
    mm.y = fmaxf(fmaxf(a0.y, a1.y), fmaxf(a2.y, a3.y));
    mm.z = fmaxf(fmaxf(a0.z, a1.z), fmaxf(a2.z, a3.z));
    mm.w = fmaxf(fmaxf(a0.w, a1.w), fmaxf(a2.w, a3.w));
    *(float4*)(mdstv + (size_t)(i0 + t) * 4) = mm;
  }
}

// ---------------- k3: barrier-free MFMA softmax+PV, wave = head ----------------
// grid = 128 rowblocks (32 rows) x 4 j-splits (1024 j each) = 512 blocks
__global__ __launch_bounds__(256) void k3_mfma(
    const unsigned short* __restrict__ WhT, const float* __restrict__ srcv,
    const float* __restrict__ dstv_soa, const float* __restrict__ mdstv,
    const u64* __restrict__ bmask,
    float* __restrict__ pacc, float* __restrict__ pden)
{
  const int t = threadIdx.x;
  const int rb = blockIdx.x & 127, s = blockIdx.x >> 7;
  const int i0 = rb * 32;
  const int w0 = s * 16;
  const int h  = t >> 6;     // wave = head
  const int l  = t & 63;
  const int r  = l & 15;     // fragment row/col
  const int g  = l >> 4;     // k-group

  // per-lane row scalars (rows i0+r and i0+16+r, head h)
  const float sr0 = srcv[(size_t)(i0 + r) * 4 + h];
  const float sr1 = srcv[(size_t)(i0 + 16 + r) * 4 + h];
  const float md0 = mdstv[(size_t)(i0 + r) * 4 + h];
  const float md1 = mdstv[(size_t)(i0 + 16 + r) * 4 + h];
  const bool u0 = (md0 == -FLTMAX), u1 = (md1 == -FLTMAX);
  const float mr0 = lrelu(sr0 + md0), mr1 = lrelu(sr1 + md1);

  f32x4 acc[2][4];
#pragma unroll
  for (int m = 0; m < 2; ++m)
#pragma unroll
    for (int n = 0; n < 4; ++n) acc[m][n] = (f32x4){0.f, 0.f, 0.f, 0.f};
  float dacc0 = 0.f, dacc1 = 0.f;

  const unsigned short* whb = WhT + (size_t)(h * 64 + r) * NN + s * 1024 + g * 8;
  const float* dpb = dstv_soa + (size_t)h * NN + s * 1024 + g * 8;
  const u64* mb0 = bmask + (size_t)(i0 + r) * 64 + w0;
  const u64* mb1 = bmask + (size_t)(i0 + 16 + r) * 64 + w0;

  for (int tile = 0; tile < 16; ++tile) {
    const u64 wm0 = mb0[tile];
    const u64 wm1 = mb1[tile];
#pragma unroll
    for (int kt = 0; kt < 2; ++kt) {
      float4 da = *(const float4*)(dpb + tile * 64 + kt * 32);
      float4 db = *(const float4*)(dpb + tile * 64 + kt * 32 + 4);
      const unsigned bits0 = (unsigned)(wm0 >> (kt * 32 + g * 8)) & 0xffu;
      const unsigned bits1 = (unsigned)(wm1 >> (kt * 32 + g * 8)) & 0xffu;
      const float dvs[8] = {da.x, da.y, da.z, da.w, db.x, db.y, db.z, db.w};
      short8x a0, a1;
#pragma unroll
      for (int jj = 0; jj < 8; ++jj) {
        float e0 = lrelu(sr0 + dvs[jj]);
        float p0 = ((bits0 >> jj) & 1u) ? __expf(e0 - mr0) : 0.f;
        p0 = u0 ? 1.f : p0;
        unsigned short pb0 = f2bf(p0);
        a0[jj] = (short)pb0;
        dacc0 += bf2f(pb0);
        float e1 = lrelu(sr1 + dvs[jj]);
        float p1 = ((bits1 >> jj) & 1u) ? __expf(e1 - mr1) : 0.f;
        p1 = u1 ? 1.f : p1;
        unsigned short pb1 = f2bf(p1);
        a1[jj] = (short)pb1;
        dacc1 += bf2f(pb1);
      }
      short8x bfr[4];
#pragma unroll
      for (int n = 0; n < 4; ++n)
        bfr[n] = *(const short8x*)(whb + (size_t)(n * 16) * NN + tile * 64 + kt * 32);
#pragma unroll
      for (int n = 0; n < 4; ++n) {
        acc[0][n] = __builtin_amdgcn_mfma_f32_16x16x32_bf16(a0, bfr[n], acc[0][n], 0, 0, 0);
        acc[1][n] = __builtin_amdgcn_mfma_f32_16x16x32_bf16(a1, bfr[n], acc[1][n], 0, 0, 0);
      }
    }
  }

  // denominator: sum over k-groups (lanes r, r+16, r+32, r+48)
  dacc0 += __shfl_xor(dacc0, 16); dacc0 += __shfl_xor(dacc0, 32);
  dacc1 += __shfl_xor(dacc1, 16); dacc1 += __shfl_xor(dacc1, 32);
  if (l < 16) {
    pden[((size_t)s * NN + i0 + l) * 4 + h] = dacc0;
    pden[((size_t)s * NN + i0 + 16 + l) * 4 + h] = dacc1;
  }

  // C/D: col = l&15, row = 4*(l>>4)+reg
#pragma unroll
  for (int m = 0; m < 2; ++m)
#pragma unroll
    for (int n = 0; n < 4; ++n)
#pragma unroll
      for (int q = 0; q < 4; ++q)
        pacc[((size_t)s * NN + i0 + 16 * m + g * 4 + q) * 256 + h * 64 + n * 16 + r] = acc[m][n][q];
}

// ---------------- k4: combine partials, divide ----------------
__global__ __launch_bounds__(256) void k4_combine(
    const float* __restrict__ pacc, const float* __restrict__ pden,
    float* __restrict__ out)
{
  const int t = threadIdx.x;
  const int i = blockIdx.x * 4 + (t >> 6);
  const int c4 = t & 63;          // float4 column index
  const int h = c4 >> 4;
  const float4* pa = (const float4*)pacc;
  float4 num = {0.f, 0.f, 0.f, 0.f};
  float den = 0.f;
#pragma unroll
  for (int s = 0; s < 4; ++s) {
    float4 v = pa[((size_t)(s * NN + i)) * 64 + c4];
    num.x += v.x; num.y += v.y; num.z += v.z; num.w += v.w;
    den += pden[((size_t)s * NN + i) * 4 + h];
  }
  float inv = 1.f / den;
  float4 o = {num.x * inv, num.y * inv, num.z * inv, num.w * inv};
  ((float4*)out)[(size_t)i * 64 + c4] = o;
}

extern "C" void kernel_launch(void* const* d_in, const int* in_sizes, int n_in,
                              void* d_out, int out_size, void* d_ws, size_t ws_size,
                              hipStream_t stream) {
  const float* hin  = (const float*)d_in[0];
  const int*   adj  = (const int*)d_in[1];
  const float* W    = (const float*)d_in[2];
  const float* bias = (const float*)d_in[3];
  const float* av   = (const float*)d_in[4];
  float* out = (float*)d_out;

  char* ws = (char*)d_ws;
  unsigned short* WhT = (unsigned short*)ws;                    // 2 MB
  float* srcv  = (float*)(ws + (2u << 20));                     // 64 KB
  float* dstv  = srcv + NN * 4;                                 // 64 KB (SoA [4][NN])
  float* mdstv = dstv + NN * 4;                                 // 64 KB
  u64* bmask   = (u64*)(ws + (2u << 20) + 196608);              // 2 MB
  float* pacc  = (float*)(ws + (2u << 20) + 196608 + (2u << 20)); // 16 MB
  float* pden  = pacc + (size_t)4 * NN * 256;                   // 256 KB

  k1_gemm<<<NN / K1R, 256, 0, stream>>>(hin, W, bias, av, WhT, srcv, dstv);
  k2_mask<<<NN / 8, 256, 0, stream>>>(adj, dstv, bmask, mdstv);
  k3_mfma<<<512, 256, 0, stream>>>(WhT, srcv, dstv, mdstv, bmask, pacc, pden);
  k4_combine<<<NN / 4, 256, 0, stream>>>(pacc, pden, out);
}

// Round 7
// 226.949 us; speedup vs baseline: 2.5463x; 1.1444x over previous
//
#include <hip/hip_runtime.h>

#define NN 4096
#define ALPHA 0.2f
#define FLTMAX 3.402823466e+38f

typedef __attribute__((ext_vector_type(8))) short short8x;
typedef __attribute__((ext_vector_type(4))) float f32x4;
typedef unsigned long long u64;

__device__ __forceinline__ float lrelu(float x) { return x > 0.f ? x : ALPHA * x; }

// round-to-nearest-even f32 -> bf16 bits
__device__ __forceinline__ unsigned short f2bf(float f) {
  unsigned u = __float_as_uint(f);
  u += 0x7fffu + ((u >> 16) & 1u);
  return (unsigned short)(u >> 16);
}
__device__ __forceinline__ float bf2f(unsigned short s) {
  return __uint_as_float(((unsigned)s) << 16);
}
// order-preserving float -> uint key (for atomicMax on floats)
__device__ __forceinline__ unsigned fkey(float f) {
  unsigned b = __float_as_uint(f);
  return (b & 0x80000000u) ? ~b : (b | 0x80000000u);
}
__device__ __forceinline__ float funkey(unsigned k) {
  return __uint_as_float((k & 0x80000000u) ? (k & 0x7fffffffu) : ~k);
}

// ---------------- k0: transpose W -> WT4[k4][t] (float4), init dmaxkey ----------------
__global__ __launch_bounds__(256) void k0_prep(
    const float* __restrict__ W, float4* __restrict__ WT4,
    unsigned* __restrict__ dmaxkey)
{
  const int t = threadIdx.x, k4 = blockIdx.x;   // 64 blocks x 256 threads
  float4 v = *(const float4*)(W + (size_t)t * 256 + k4 * 4);
  WT4[(size_t)k4 * 256 + t] = v;
  if (k4 == 0 && t < 4) dmaxkey[t] = 0x00800000u;  // fkey(-FLTMAX)
}

// ---------------- k1: Wh = h @ W.T + b; WhT bf16 [256][4096]; src/dst; dmax ----------------
// no LDS, no barriers: W chunks register-staged from WT4 (coalesced), h rows wave-uniform
#define K1R 8
__global__ __launch_bounds__(256) void k1_gemm(
    const float* __restrict__ hin, const float4* __restrict__ WT4,
    const float* __restrict__ bias, const float* __restrict__ av,
    unsigned short* __restrict__ WhT, float* __restrict__ srcv,
    float* __restrict__ dstv_soa, unsigned* __restrict__ dmaxkey)
{
  const int t = threadIdx.x;
  const int r0 = blockIdx.x * K1R;

  float acc[K1R];
#pragma unroll
  for (int r = 0; r < K1R; ++r) acc[r] = 0.f;

  for (int c = 0; c < 8; ++c) {            // K-chunks of 32
    float4 wr[8];
#pragma unroll
    for (int q = 0; q < 8; ++q) wr[q] = WT4[(size_t)(c * 8 + q) * 256 + t];
#pragma unroll
    for (int r = 0; r < K1R; ++r) {
      const float4* h4 = (const float4*)(hin + (size_t)(r0 + r) * 256 + c * 32);
      float s = acc[r];
#pragma unroll
      for (int q = 0; q < 8; ++q) {
        float4 hv = h4[q];                 // wave-uniform (scalarizable)
        s += hv.x * wr[q].x + hv.y * wr[q].y + hv.z * wr[q].z + hv.w * wr[q].w;
      }
      acc[r] = s;
    }
  }

  const int hh = t >> 6, lane = t & 63;
  const float asrc = av[hh * 128 + lane];
  const float adst = av[hh * 128 + 64 + lane];
  const float bc = bias[t];
  unsigned short wb[K1R];
  float dm = -FLTMAX;
#pragma unroll
  for (int r = 0; r < K1R; ++r) {
    float w = acc[r] + bc;
    wb[r] = f2bf(w);
    float s = w * asrc, d = w * adst;
#pragma unroll
    for (int off = 32; off >= 1; off >>= 1) {
      s += __shfl_xor(s, off);
      d += __shfl_xor(d, off);
    }
    dm = fmaxf(dm, d);
    if (lane == 0) {
      srcv[(size_t)(r0 + r) * 4 + hh] = s;
      dstv_soa[(size_t)hh * NN + r0 + r] = d;
    }
  }
  if (lane == 0) atomicMax(dmaxkey + hh, fkey(dm));
  // thread t holds column t for rows r0..r0+7 -> transposed store is contiguous
  {
    short8x v;
#pragma unroll
    for (int r = 0; r < K1R; ++r) v[r] = (short)wb[r];
    *(short8x*)(WhT + (size_t)t * NN + r0) = v;
  }
}

// ---------------- k2: adj -> bitmask (pure streaming, wave = row) ----------------
__global__ __launch_bounds__(256) void k2_mask(
    const int* __restrict__ adj, u64* __restrict__ bmask)
{
  const int t = threadIdx.x, wid = t >> 6, l = t & 63;
  const int row = blockIdx.x * 4 + wid;
  const int4* ap = (const int4*)(adj + (size_t)row * NN) + l;
  const int sh = 4 * (l & 15);
#pragma unroll
  for (int it = 0; it < 16; ++it) {
    int4 v = ap[(size_t)it * 64];
    unsigned nib = (v.x & 1) | ((v.y & 1) << 1) | ((v.z & 1) << 2) | ((v.w & 1) << 3);
    u64 w = (u64)nib << sh;
    w |= __shfl_xor(w, 1);
    w |= __shfl_xor(w, 2);
    w |= __shfl_xor(w, 4);
    w |= __shfl_xor(w, 8);
    if ((l & 15) == 0) bmask[(size_t)row * 64 + it * 4 + (l >> 4)] = w;
  }
}

// ---------------- k3: barrier-free MFMA softmax+PV, wave = head ----------------
// grid = 128 rowblocks (32 rows) x 4 j-splits (1024 j each) = 512 blocks
__global__ __launch_bounds__(256) void k3_mfma(
    const unsigned short* __restrict__ WhT, const float* __restrict__ srcv,
    const float* __restrict__ dstv_soa, const unsigned* __restrict__ dmaxkey,
    const u64* __restrict__ bmask,
    float* __restrict__ pacc, float* __restrict__ pden)
{
  const int t = threadIdx.x;
  const int rb = blockIdx.x & 127, s = blockIdx.x >> 7;
  const int i0 = rb * 32;
  const int w0 = s * 16;
  const int h  = t >> 6;     // wave = head
  const int l  = t & 63;
  const int r  = l & 15;     // fragment row/col
  const int g  = l >> 4;     // k-group

  const float dmax = funkey(dmaxkey[h]);
  // per-lane row scalars (rows i0+r and i0+16+r, head h)
  const float sr0 = srcv[(size_t)(i0 + r) * 4 + h];
  const float sr1 = srcv[(size_t)(i0 + 16 + r) * 4 + h];
  const float mr0 = lrelu(sr0 + dmax), mr1 = lrelu(sr1 + dmax);

  f32x4 acc[2][4];
#pragma unroll
  for (int m = 0; m < 2; ++m)
#pragma unroll
    for (int n = 0; n < 4; ++n) acc[m][n] = (f32x4){0.f, 0.f, 0.f, 0.f};
  float dacc0 = 0.f, dacc1 = 0.f;

  const unsigned short* whb = WhT + (size_t)(h * 64 + r) * NN + s * 1024 + g * 8;
  const float* dpb = dstv_soa + (size_t)h * NN + s * 1024 + g * 8;
  const u64* mb0 = bmask + (size_t)(i0 + r) * 64 + w0;
  const u64* mb1 = bmask + (size_t)(i0 + 16 + r) * 64 + w0;

  for (int tile = 0; tile < 16; ++tile) {
    const u64 wm0 = mb0[tile];
    const u64 wm1 = mb1[tile];
#pragma unroll
    for (int kt = 0; kt < 2; ++kt) {
      float4 da = *(const float4*)(dpb + tile * 64 + kt * 32);
      float4 db = *(const float4*)(dpb + tile * 64 + kt * 32 + 4);
      const unsigned bits0 = (unsigned)(wm0 >> (kt * 32 + g * 8)) & 0xffu;
      const unsigned bits1 = (unsigned)(wm1 >> (kt * 32 + g * 8)) & 0xffu;
      const float dvs[8] = {da.x, da.y, da.z, da.w, db.x, db.y, db.z, db.w};
      short8x a0, a1;
#pragma unroll
      for (int jj = 0; jj < 8; ++jj) {
        float e0 = lrelu(sr0 + dvs[jj]);
        float p0 = ((bits0 >> jj) & 1u) ? __expf(e0 - mr0) : 0.f;
        unsigned short pb0 = f2bf(p0);
        a0[jj] = (short)pb0;
        dacc0 += bf2f(pb0);
        float e1 = lrelu(sr1 + dvs[jj]);
        float p1 = ((bits1 >> jj) & 1u) ? __expf(e1 - mr1) : 0.f;
        unsigned short pb1 = f2bf(p1);
        a1[jj] = (short)pb1;
        dacc1 += bf2f(pb1);
      }
      short8x bfr[4];
#pragma unroll
      for (int n = 0; n < 4; ++n)
        bfr[n] = *(const short8x*)(whb + (size_t)(n * 16) * NN + tile * 64 + kt * 32);
#pragma unroll
      for (int n = 0; n < 4; ++n) {
        acc[0][n] = __builtin_amdgcn_mfma_f32_16x16x32_bf16(a0, bfr[n], acc[0][n], 0, 0, 0);
        acc[1][n] = __builtin_amdgcn_mfma_f32_16x16x32_bf16(a1, bfr[n], acc[1][n], 0, 0, 0);
      }
    }
  }

  // denominator: sum over k-groups (lanes r, r+16, r+32, r+48)
  dacc0 += __shfl_xor(dacc0, 16); dacc0 += __shfl_xor(dacc0, 32);
  dacc1 += __shfl_xor(dacc1, 16); dacc1 += __shfl_xor(dacc1, 32);
  if (l < 16) {
    pden[((size_t)s * NN + i0 + l) * 4 + h] = dacc0;
    pden[((size_t)s * NN + i0 + 16 + l) * 4 + h] = dacc1;
  }

  // C/D: col = l&15, row = 4*(l>>4)+reg
#pragma unroll
  for (int m = 0; m < 2; ++m)
#pragma unroll
    for (int n = 0; n < 4; ++n)
#pragma unroll
      for (int q = 0; q < 4; ++q)
        pacc[((size_t)s * NN + i0 + 16 * m + g * 4 + q) * 256 + h * 64 + n * 16 + r] = acc[m][n][q];
}

// ---------------- k4: combine partials, divide ----------------
__global__ __launch_bounds__(256) void k4_combine(
    const float* __restrict__ pacc, const float* __restrict__ pden,
    float* __restrict__ out)
{
  const int t = threadIdx.x;
  const int i = blockIdx.x * 4 + (t >> 6);
  const int c4 = t & 63;          // float4 column index
  const int h = c4 >> 4;
  const float4* pa = (const float4*)pacc;
  float4 num = {0.f, 0.f, 0.f, 0.f};
  float den = 0.f;
#pragma unroll
  for (int s = 0; s < 4; ++s) {
    float4 v = pa[((size_t)(s * NN + i)) * 64 + c4];
    num.x += v.x; num.y += v.y; num.z += v.z; num.w += v.w;
    den += pden[((size_t)s * NN + i) * 4 + h];
  }
  float inv = 1.f / den;
  float4 o = {num.x * inv, num.y * inv, num.z * inv, num.w * inv};
  ((float4*)out)[(size_t)i * 64 + c4] = o;
}

extern "C" void kernel_launch(void* const* d_in, const int* in_sizes, int n_in,
                              void* d_out, int out_size, void* d_ws, size_t ws_size,
                              hipStream_t stream) {
  const float* hin  = (const float*)d_in[0];
  const int*   adj  = (const int*)d_in[1];
  const float* W    = (const float*)d_in[2];
  const float* bias = (const float*)d_in[3];
  const float* av   = (const float*)d_in[4];
  float* out = (float*)d_out;

  char* ws = (char*)d_ws;
  unsigned short* WhT = (unsigned short*)(ws + 0x0);          // 2 MB
  float4* WT4  = (float4*)(ws + 0x200000);                    // 256 KB
  float* srcv  = (float*)(ws + 0x240000);                     // 64 KB
  float* dstv  = (float*)(ws + 0x250000);                     // 64 KB (SoA [4][NN])
  unsigned* dmaxkey = (unsigned*)(ws + 0x260000);             // 16 B (pad)
  u64* bmask   = (u64*)(ws + 0x261000);                       // 2 MB
  float* pacc  = (float*)(ws + 0x461000);                     // 16 MB
  float* pden  = (float*)(ws + 0x1461000);                    // 256 KB

  k0_prep<<<64, 256, 0, stream>>>(W, WT4, dmaxkey);
  k1_gemm<<<NN / K1R, 256, 0, stream>>>(hin, WT4, bias, av, WhT, srcv, dstv, dmaxkey);
  k2_mask<<<NN / 4, 256, 0, stream>>>(adj, bmask);
  k3_mfma<<<512, 256, 0, stream>>>(WhT, srcv, dstv, dmaxkey, bmask, pacc, pden);
  k4_combine<<<NN / 4, 256, 0, stream>>>(pacc, pden, out);
}

// Round 8
// 212.398 us; speedup vs baseline: 2.7208x; 1.0685x over previous
//
#include <hip/hip_runtime.h>

#define NN 4096
#define ALPHA 0.2f
#define FLTMAX 3.402823466e+38f

typedef __attribute__((ext_vector_type(8))) short short8x;
typedef __attribute__((ext_vector_type(4))) float f32x4;
typedef __attribute__((ext_vector_type(4))) unsigned short ushort4x;
typedef unsigned long long u64;

__device__ __forceinline__ float lrelu(float x) { return x > 0.f ? x : ALPHA * x; }

// round-to-nearest-even f32 -> bf16 bits
__device__ __forceinline__ unsigned short f2bf(float f) {
  unsigned u = __float_as_uint(f);
  u += 0x7fffu + ((u >> 16) & 1u);
  return (unsigned short)(u >> 16);
}
__device__ __forceinline__ float bf2f(unsigned short s) {
  return __uint_as_float(((unsigned)s) << 16);
}
// order-preserving float -> uint key (for atomicMax on floats)
__device__ __forceinline__ unsigned fkey(float f) {
  unsigned b = __float_as_uint(f);
  return (b & 0x80000000u) ? ~b : (b | 0x80000000u);
}
__device__ __forceinline__ float funkey(unsigned k) {
  return __uint_as_float((k & 0x80000000u) ? (k & 0x7fffffffu) : ~k);
}

// ---------------- k0: W -> bf16 hi/lo split Whi/Wlo [d][k]; init dmaxkey ----------------
__global__ __launch_bounds__(256) void k0_prep(
    const float* __restrict__ W, unsigned short* __restrict__ Whi,
    unsigned short* __restrict__ Wlo, unsigned* __restrict__ dmaxkey)
{
  const int t = threadIdx.x;
  const int idx = blockIdx.x * 256 + t;      // 64 blocks: 16384 float4 = 256*256 floats
  float4 v = ((const float4*)W)[idx];
  const float vf[4] = {v.x, v.y, v.z, v.w};
  ushort4x hi, lo;
#pragma unroll
  for (int q = 0; q < 4; ++q) {
    unsigned short hb = f2bf(vf[q]);
    hi[q] = hb;
    lo[q] = f2bf(vf[q] - bf2f(hb));
  }
  ((ushort4x*)Whi)[idx] = hi;
  ((ushort4x*)Wlo)[idx] = lo;
  if (blockIdx.x == 0 && t < 4) dmaxkey[t] = 0x00800000u;  // fkey(-FLTMAX)
}

// ---------------- k1: MFMA Wh = h @ W.T + b (bf16 hi/lo, ~f32 accurate) ----------------
// grid = 256 rowblocks (16 rows) x 4 heads = 1024 blocks; wave w = head-cols 16w..16w+15
__global__ __launch_bounds__(256) void k1_mfma(
    const float* __restrict__ hin, const unsigned short* __restrict__ Whi,
    const unsigned short* __restrict__ Wlo, const float* __restrict__ bias,
    const float* __restrict__ av, unsigned short* __restrict__ WhT,
    float* __restrict__ srcv, float* __restrict__ dstv_soa,
    unsigned* __restrict__ dmaxkey)
{
  __shared__ float lds_s[4][16], lds_d[4][16];
  const int t = threadIdx.x;
  const int rb = blockIdx.x >> 2, h = blockIdx.x & 3;
  const int m0 = rb * 16;
  const int w = t >> 6, l = t & 63, r = l & 15, g = l >> 4;
  const int d = w * 16 + r;              // within-head output dim
  const int col = h * 64 + d;            // global output dim

  f32x4 acc = (f32x4){0.f, 0.f, 0.f, 0.f};
  const float* arow = hin + (size_t)(m0 + r) * 256 + g * 8;   // A: row m0+r, k=8g+j
  const unsigned short* bh = Whi + (size_t)col * 256 + g * 8; // B: col, k=8g+j
  const unsigned short* bl = Wlo + (size_t)col * 256 + g * 8;

#pragma unroll
  for (int ks = 0; ks < 8; ++ks) {       // k0 = 32*ks
    float4 a0 = *(const float4*)(arow + ks * 32);
    float4 a1 = *(const float4*)(arow + ks * 32 + 4);
    const float af[8] = {a0.x, a0.y, a0.z, a0.w, a1.x, a1.y, a1.z, a1.w};
    short8x ahi, alo;
#pragma unroll
    for (int j = 0; j < 8; ++j) {
      unsigned short hb = f2bf(af[j]);
      ahi[j] = (short)hb;
      alo[j] = (short)f2bf(af[j] - bf2f(hb));
    }
    short8x bhf = *(const short8x*)(bh + ks * 32);
    short8x blf = *(const short8x*)(bl + ks * 32);
    acc = __builtin_amdgcn_mfma_f32_16x16x32_bf16(ahi, bhf, acc, 0, 0, 0);
    acc = __builtin_amdgcn_mfma_f32_16x16x32_bf16(ahi, blf, acc, 0, 0, 0);
    acc = __builtin_amdgcn_mfma_f32_16x16x32_bf16(alo, bhf, acc, 0, 0, 0);
  }

  // epilogue: lane holds Wh rows m0+4g+q (q=0..3), col
  const float bc = bias[col];
  const float asrc = av[h * 128 + d];
  const float adst = av[h * 128 + 64 + d];
  float wv[4];
  ushort4x st;
#pragma unroll
  for (int q = 0; q < 4; ++q) {
    wv[q] = acc[q] + bc;
    st[q] = f2bf(wv[q]);
  }
  *(ushort4x*)(WhT + (size_t)col * NN + m0 + 4 * g) = st;

#pragma unroll
  for (int q = 0; q < 4; ++q) {
    float s = wv[q] * asrc, dd = wv[q] * adst;
#pragma unroll
    for (int off = 8; off >= 1; off >>= 1) {     // reduce over 16 cols (lanes r)
      s += __shfl_xor(s, off);
      dd += __shfl_xor(dd, off);
    }
    if (r == 0) { lds_s[w][4 * g + q] = s; lds_d[w][4 * g + q] = dd; }
  }
  __syncthreads();
  if (t < 64) {                                   // wave 0: combine 4 waves
    const int row = t & 15;
    float s = lds_s[0][row] + lds_s[1][row] + lds_s[2][row] + lds_s[3][row];
    float dd = lds_d[0][row] + lds_d[1][row] + lds_d[2][row] + lds_d[3][row];
    if (t < 16) {
      srcv[(size_t)(m0 + row) * 4 + h] = s;
      dstv_soa[(size_t)h * NN + m0 + row] = dd;
    }
    float m = dd;
#pragma unroll
    for (int off = 1; off <= 32; off <<= 1) m = fmaxf(m, __shfl_xor(m, off));
    if (t == 0) atomicMax(dmaxkey + h, fkey(m));
  }
}

// ---------------- k2: adj -> bitmask (pure streaming, wave = row) ----------------
__global__ __launch_bounds__(256) void k2_mask(
    const int* __restrict__ adj, u64* __restrict__ bmask)
{
  const int t = threadIdx.x, wid = t >> 6, l = t & 63;
  const int row = blockIdx.x * 4 + wid;
  const int4* ap = (const int4*)(adj + (size_t)row * NN) + l;
  const int sh = 4 * (l & 15);
#pragma unroll
  for (int it = 0; it < 16; ++it) {
    int4 v = ap[(size_t)it * 64];
    unsigned nib = (v.x & 1) | ((v.y & 1) << 1) | ((v.z & 1) << 2) | ((v.w & 1) << 3);
    u64 w = (u64)nib << sh;
    w |= __shfl_xor(w, 1);
    w |= __shfl_xor(w, 2);
    w |= __shfl_xor(w, 4);
    w |= __shfl_xor(w, 8);
    if ((l & 15) == 0) bmask[(size_t)row * 64 + it * 4 + (l >> 4)] = w;
  }
}

// ---------------- k3: barrier-free MFMA softmax+PV, wave = head ----------------
// grid = 256 rowblocks (16 rows) x 4 j-splits (1024 j each) = 1024 blocks
__global__ __launch_bounds__(256) void k3_mfma(
    const unsigned short* __restrict__ WhT, const float* __restrict__ srcv,
    const float* __restrict__ dstv_soa, const unsigned* __restrict__ dmaxkey,
    const u64* __restrict__ bmask,
    float* __restrict__ pacc, float* __restrict__ pden)
{
  const int t = threadIdx.x;
  const int rb = blockIdx.x & 255, s = blockIdx.x >> 8;
  const int i0 = rb * 16;
  const int w0 = s * 16;
  const int h  = t >> 6;     // wave = head
  const int l  = t & 63;
  const int r  = l & 15;     // fragment row/col
  const int g  = l >> 4;     // k-group

  const float dmax = funkey(dmaxkey[h]);
  const float sr0 = srcv[(size_t)(i0 + r) * 4 + h];
  const float mr0 = lrelu(sr0 + dmax);

  f32x4 acc[4];
#pragma unroll
  for (int n = 0; n < 4; ++n) acc[n] = (f32x4){0.f, 0.f, 0.f, 0.f};
  float dacc0 = 0.f;

  const unsigned short* whb = WhT + (size_t)(h * 64 + r) * NN + s * 1024 + g * 8;
  const float* dpb = dstv_soa + (size_t)h * NN + s * 1024 + g * 8;
  const u64* mb0 = bmask + (size_t)(i0 + r) * 64 + w0;

  for (int tile = 0; tile < 16; ++tile) {
    const u64 wm0 = mb0[tile];
#pragma unroll
    for (int kt = 0; kt < 2; ++kt) {
      float4 da = *(const float4*)(dpb + tile * 64 + kt * 32);
      float4 db = *(const float4*)(dpb + tile * 64 + kt * 32 + 4);
      const unsigned bits0 = (unsigned)(wm0 >> (kt * 32 + g * 8)) & 0xffu;
      const float dvs[8] = {da.x, da.y, da.z, da.w, db.x, db.y, db.z, db.w};
      short8x a0;
#pragma unroll
      for (int jj = 0; jj < 8; ++jj) {
        float e0 = lrelu(sr0 + dvs[jj]);
        float p0 = ((bits0 >> jj) & 1u) ? __expf(e0 - mr0) : 0.f;
        unsigned short pb0 = f2bf(p0);
        a0[jj] = (short)pb0;
        dacc0 += bf2f(pb0);
      }
      short8x bfr[4];
#pragma unroll
      for (int n = 0; n < 4; ++n)
        bfr[n] = *(const short8x*)(whb + (size_t)(n * 16) * NN + tile * 64 + kt * 32);
#pragma unroll
      for (int n = 0; n < 4; ++n)
        acc[n] = __builtin_amdgcn_mfma_f32_16x16x32_bf16(a0, bfr[n], acc[n], 0, 0, 0);
    }
  }

  // denominator: sum over k-groups (lanes r, r+16, r+32, r+48)
  dacc0 += __shfl_xor(dacc0, 16); dacc0 += __shfl_xor(dacc0, 32);
  if (l < 16) pden[((size_t)s * NN + i0 + l) * 4 + h] = dacc0;

  // C/D: col = l&15, row = 4*(l>>4)+reg
#pragma unroll
  for (int n = 0; n < 4; ++n)
#pragma unroll
    for (int q = 0; q < 4; ++q)
      pacc[((size_t)s * NN + i0 + g * 4 + q) * 256 + h * 64 + n * 16 + r] = acc[n][q];
}

// ---------------- k4: combine partials, divide ----------------
__global__ __launch_bounds__(256) void k4_combine(
    const float* __restrict__ pacc, const float* __restrict__ pden,
    float* __restrict__ out)
{
  const int t = threadIdx.x;
  const int i = blockIdx.x * 4 + (t >> 6);
  const int c4 = t & 63;          // float4 column index
  const int h = c4 >> 4;
  const float4* pa = (const float4*)pacc;
  float4 num = {0.f, 0.f, 0.f, 0.f};
  float den = 0.f;
#pragma unroll
  for (int s = 0; s < 4; ++s) {
    float4 v = pa[((size_t)(s * NN + i)) * 64 + c4];
    num.x += v.x; num.y += v.y; num.z += v.z; num.w += v.w;
    den += pden[((size_t)s * NN + i) * 4 + h];
  }
  float inv = 1.f / den;
  float4 o = {num.x * inv, num.y * inv, num.z * inv, num.w * inv};
  ((float4*)out)[(size_t)i * 64 + c4] = o;
}

extern "C" void kernel_launch(void* const* d_in, const int* in_sizes, int n_in,
                              void* d_out, int out_size, void* d_ws, size_t ws_size,
                              hipStream_t stream) {
  const float* hin  = (const float*)d_in[0];
  const int*   adj  = (const int*)d_in[1];
  const float* W    = (const float*)d_in[2];
  const float* bias = (const float*)d_in[3];
  const float* av   = (const float*)d_in[4];
  float* out = (float*)d_out;

  char* ws = (char*)d_ws;
  unsigned short* WhT = (unsigned short*)(ws + 0x0);          // 2 MB
  unsigned short* Whi = (unsigned short*)(ws + 0x200000);     // 128 KB
  unsigned short* Wlo = (unsigned short*)(ws + 0x220000);     // 128 KB
  float* srcv  = (float*)(ws + 0x240000);                     // 64 KB
  float* dstv  = (float*)(ws + 0x250000);                     // 64 KB (SoA [4][NN])
  unsigned* dmaxkey = (unsigned*)(ws + 0x260000);             // 16 B (pad)
  u64* bmask   = (u64*)(ws + 0x261000);                       // 2 MB
  float* pacc  = (float*)(ws + 0x461000);                     // 16 MB
  float* pden  = (float*)(ws + 0x1461000);                    // 256 KB

  k0_prep<<<64, 256, 0, stream>>>(W, Whi, Wlo, dmaxkey);
  k1_mfma<<<1024, 256, 0, stream>>>(hin, Whi, Wlo, bias, av, WhT, srcv, dstv, dmaxkey);
  k2_mask<<<1024, 256, 0, stream>>>(adj, bmask);
  k3_mfma<<<1024, 256, 0, stream>>>(WhT, srcv, dstv, dmaxkey, bmask, pacc, pden);
  k4_combine<<<NN / 4, 256, 0, stream>>>(pacc, pden, out);
}

// Round 9
// 184.917 us; speedup vs baseline: 3.1251x; 1.1486x over previous
//
#include <hip/hip_runtime.h>

#define NN 4096
#define ALPHA 0.2f
#define FLTMAX 3.402823466e+38f
#define LOG2E 1.44269504088896340736f

typedef __attribute__((ext_vector_type(8))) short short8x;
typedef __attribute__((ext_vector_type(4))) float f32x4;
typedef __attribute__((ext_vector_type(4))) unsigned short ushort4x;
typedef unsigned long long u64;

// round-to-nearest-even f32 -> bf16 bits
__device__ __forceinline__ unsigned short f2bf(float f) {
  unsigned u = __float_as_uint(f);
  u += 0x7fffu + ((u >> 16) & 1u);
  return (unsigned short)(u >> 16);
}
__device__ __forceinline__ float bf2f(unsigned short s) {
  return __uint_as_float(((unsigned)s) << 16);
}
// order-preserving float -> uint key (for atomicMax on floats)
__device__ __forceinline__ unsigned fkey(float f) {
  unsigned b = __float_as_uint(f);
  return (b & 0x80000000u) ? ~b : (b | 0x80000000u);
}
__device__ __forceinline__ float funkey(unsigned k) {
  return __uint_as_float((k & 0x80000000u) ? (k & 0x7fffffffu) : ~k);
}

// ---------------- k0: W -> bf16 hi/lo split Whi/Wlo [d][k]; init dmaxkey ----------------
__global__ __launch_bounds__(256) void k0_prep(
    const float* __restrict__ W, unsigned short* __restrict__ Whi,
    unsigned short* __restrict__ Wlo, unsigned* __restrict__ dmaxkey)
{
  const int t = threadIdx.x;
  const int idx = blockIdx.x * 256 + t;      // 64 blocks: 16384 float4 = 256*256 floats
  float4 v = ((const float4*)W)[idx];
  const float vf[4] = {v.x, v.y, v.z, v.w};
  ushort4x hi, lo;
#pragma unroll
  for (int q = 0; q < 4; ++q) {
    unsigned short hb = f2bf(vf[q]);
    hi[q] = hb;
    lo[q] = f2bf(vf[q] - bf2f(hb));
  }
  ((ushort4x*)Whi)[idx] = hi;
  ((ushort4x*)Wlo)[idx] = lo;
  if (blockIdx.x == 0 && t < 4) dmaxkey[t] = 0x00800000u;  // fkey(-FLTMAX)
}

// ---------------- k1: MFMA Wh = h @ W.T + b (bf16 hi/lo, ~f32 accurate) ----------------
// grid = 256 rowblocks (16 rows) x 4 heads = 1024 blocks; wave w = head-cols 16w..16w+15
// src/dst/dmax stored PRE-SCALED by log2(e) so k3 can use exp2 directly.
__global__ __launch_bounds__(256) void k1_mfma(
    const float* __restrict__ hin, const unsigned short* __restrict__ Whi,
    const unsigned short* __restrict__ Wlo, const float* __restrict__ bias,
    const float* __restrict__ av, unsigned short* __restrict__ WhT,
    float* __restrict__ srcv, float* __restrict__ dstv_soa,
    unsigned* __restrict__ dmaxkey)
{
  __shared__ float lds_s[4][16], lds_d[4][16];
  const int t = threadIdx.x;
  const int rb = blockIdx.x >> 2, h = blockIdx.x & 3;
  const int m0 = rb * 16;
  const int w = t >> 6, l = t & 63, r = l & 15, g = l >> 4;
  const int d = w * 16 + r;              // within-head output dim
  const int col = h * 64 + d;            // global output dim

  f32x4 acc = (f32x4){0.f, 0.f, 0.f, 0.f};
  const float* arow = hin + (size_t)(m0 + r) * 256 + g * 8;   // A: row m0+r, k=8g+j
  const unsigned short* bh = Whi + (size_t)col * 256 + g * 8; // B: col, k=8g+j
  const unsigned short* bl = Wlo + (size_t)col * 256 + g * 8;

#pragma unroll
  for (int ks = 0; ks < 8; ++ks) {       // k0 = 32*ks
    float4 a0 = *(const float4*)(arow + ks * 32);
    float4 a1 = *(const float4*)(arow + ks * 32 + 4);
    const float af[8] = {a0.x, a0.y, a0.z, a0.w, a1.x, a1.y, a1.z, a1.w};
    short8x ahi, alo;
#pragma unroll
    for (int j = 0; j < 8; ++j) {
      unsigned short hb = f2bf(af[j]);
      ahi[j] = (short)hb;
      alo[j] = (short)f2bf(af[j] - bf2f(hb));
    }
    short8x bhf = *(const short8x*)(bh + ks * 32);
    short8x blf = *(const short8x*)(bl + ks * 32);
    acc = __builtin_amdgcn_mfma_f32_16x16x32_bf16(ahi, bhf, acc, 0, 0, 0);
    acc = __builtin_amdgcn_mfma_f32_16x16x32_bf16(ahi, blf, acc, 0, 0, 0);
    acc = __builtin_amdgcn_mfma_f32_16x16x32_bf16(alo, bhf, acc, 0, 0, 0);
  }

  // epilogue: lane holds Wh rows m0+4g+q (q=0..3), col
  const float bc = bias[col];
  const float asrc = av[h * 128 + d];
  const float adst = av[h * 128 + 64 + d];
  float wv[4];
  ushort4x st;
#pragma unroll
  for (int q = 0; q < 4; ++q) {
    wv[q] = acc[q] + bc;
    st[q] = f2bf(wv[q]);
  }
  *(ushort4x*)(WhT + (size_t)col * NN + m0 + 4 * g) = st;

#pragma unroll
  for (int q = 0; q < 4; ++q) {
    float s = wv[q] * asrc, dd = wv[q] * adst;
#pragma unroll
    for (int off = 8; off >= 1; off >>= 1) {     // reduce over 16 cols (lanes r)
      s += __shfl_xor(s, off);
      dd += __shfl_xor(dd, off);
    }
    if (r == 0) { lds_s[w][4 * g + q] = s * LOG2E; lds_d[w][4 * g + q] = dd * LOG2E; }
  }
  __syncthreads();
  if (t < 64) {                                   // wave 0: combine 4 waves
    const int row = t & 15;
    float s = lds_s[0][row] + lds_s[1][row] + lds_s[2][row] + lds_s[3][row];
    float dd = lds_d[0][row] + lds_d[1][row] + lds_d[2][row] + lds_d[3][row];
    if (t < 16) {
      srcv[(size_t)(m0 + row) * 4 + h] = s;
      dstv_soa[(size_t)h * NN + m0 + row] = dd;
    }
    float m = dd;
#pragma unroll
    for (int off = 1; off <= 32; off <<= 1) m = fmaxf(m, __shfl_xor(m, off));
    if (t == 0) atomicMax(dmaxkey + h, fkey(m));
  }
}

// ---------------- k2: adj -> bitmask (pure streaming, wave = row) ----------------
__global__ __launch_bounds__(256) void k2_mask(
    const int* __restrict__ adj, u64* __restrict__ bmask)
{
  const int t = threadIdx.x, wid = t >> 6, l = t & 63;
  const int row = blockIdx.x * 4 + wid;
  const int4* ap = (const int4*)(adj + (size_t)row * NN) + l;
  const int sh = 4 * (l & 15);
#pragma unroll
  for (int it = 0; it < 16; ++it) {
    int4 v = ap[(size_t)it * 64];
    unsigned nib = (v.x & 1) | ((v.y & 1) << 1) | ((v.z & 1) << 2) | ((v.w & 1) << 3);
    u64 w = (u64)nib << sh;
    w |= __shfl_xor(w, 1);
    w |= __shfl_xor(w, 2);
    w |= __shfl_xor(w, 4);
    w |= __shfl_xor(w, 8);
    if ((l & 15) == 0) bmask[(size_t)row * 64 + it * 4 + (l >> 4)] = w;
  }
}

// ---------------- k3: MFMA softmax+PV, XCD-local combos, LDS pair-combine ----------------
// block = (32 rows, head-pair hp, j-split s); waves = (head-sel, j-half of 512)
// blockIdx = rb*8 + s*2 + hp  ->  all same-(s,hp) blocks land on one XCD (i%8 round-robin)
__global__ __launch_bounds__(256, 4) void k3_mfma(
    const unsigned short* __restrict__ WhT, const float* __restrict__ srcv,
    const float* __restrict__ dstv_soa, const unsigned* __restrict__ dmaxkey,
    const u64* __restrict__ bmask,
    float* __restrict__ pacc, float* __restrict__ pden)
{
  __shared__ float lds_acc[2][64][33];   // [hsel][lane][32 acc] pad33: conflict-free
  __shared__ float lds_den[2][64][2];
  const int t = threadIdx.x;
  const int c  = blockIdx.x & 7;
  const int s  = c >> 1, hp = c & 1;
  const int rb = blockIdx.x >> 3;
  const int i0 = rb * 32;
  const int w = t >> 6, l = t & 63;
  const int hsel = w & 1, jh = w >> 1;
  const int h = hp * 2 + hsel;
  const int r = l & 15, g = l >> 4;
  const int j0 = s * 1024 + jh * 512;

  const float dmax = funkey(dmaxkey[h]);           // log2-domain
  const float sr0 = srcv[(size_t)(i0 + r) * 4 + h];
  const float sr1 = srcv[(size_t)(i0 + 16 + r) * 4 + h];
  const float x0m = sr0 + dmax, x1m = sr1 + dmax;
  const float mr0 = fmaxf(x0m, ALPHA * x0m);       // lrelu in log2 domain
  const float mr1 = fmaxf(x1m, ALPHA * x1m);

  f32x4 acc[2][4];
#pragma unroll
  for (int m = 0; m < 2; ++m)
#pragma unroll
    for (int n = 0; n < 4; ++n) acc[m][n] = (f32x4){0.f, 0.f, 0.f, 0.f};
  float dacc0 = 0.f, dacc1 = 0.f;

  const unsigned short* whb = WhT + (size_t)(h * 64 + r) * NN + j0 + g * 8;
  const float* dpb = dstv_soa + (size_t)h * NN + j0 + g * 8;
  const u64* mb0 = bmask + (size_t)(i0 + r) * 64 + s * 16 + jh * 8;
  const u64* mb1 = bmask + (size_t)(i0 + 16 + r) * 64 + s * 16 + jh * 8;

  for (int tile = 0; tile < 8; ++tile) {
    const u64 wm0 = mb0[tile];
    const u64 wm1 = mb1[tile];
#pragma unroll
    for (int kt = 0; kt < 2; ++kt) {
      float4 da = *(const float4*)(dpb + tile * 64 + kt * 32);
      float4 db = *(const float4*)(dpb + tile * 64 + kt * 32 + 4);
      const unsigned bits0 = (unsigned)(wm0 >> (kt * 32 + g * 8)) & 0xffu;
      const unsigned bits1 = (unsigned)(wm1 >> (kt * 32 + g * 8)) & 0xffu;
      const float dvs[8] = {da.x, da.y, da.z, da.w, db.x, db.y, db.z, db.w};
      short8x a0, a1;
#pragma unroll
      for (int jj = 0; jj < 8; ++jj) {
        float x0 = sr0 + dvs[jj];
        float e0 = fmaxf(x0, ALPHA * x0) - mr0;
        e0 = ((bits0 >> jj) & 1u) ? e0 : -200.0f;
        unsigned pu0 = __float_as_uint(exp2f(e0));
        dacc0 += __uint_as_float(pu0 & 0xffff0000u);   // truncated bf16, = MFMA operand
        a0[jj] = (short)(pu0 >> 16);
        float x1 = sr1 + dvs[jj];
        float e1 = fmaxf(x1, ALPHA * x1) - mr1;
        e1 = ((bits1 >> jj) & 1u) ? e1 : -200.0f;
        unsigned pu1 = __float_as_uint(exp2f(e1));
        dacc1 += __uint_as_float(pu1 & 0xffff0000u);
        a1[jj] = (short)(pu1 >> 16);
      }
      short8x bfr[4];
#pragma unroll
      for (int n = 0; n < 4; ++n)
        bfr[n] = *(const short8x*)(whb + (size_t)(n * 16) * NN + tile * 64 + kt * 32);
#pragma unroll
      for (int n = 0; n < 4; ++n) {
        acc[0][n] = __builtin_amdgcn_mfma_f32_16x16x32_bf16(a0, bfr[n], acc[0][n], 0, 0, 0);
        acc[1][n] = __builtin_amdgcn_mfma_f32_16x16x32_bf16(a1, bfr[n], acc[1][n], 0, 0, 0);
      }
    }
  }

  // combine the two j-halves of each head via LDS
  if (jh == 1) {
#pragma unroll
    for (int m = 0; m < 2; ++m)
#pragma unroll
      for (int n = 0; n < 4; ++n)
#pragma unroll
        for (int q = 0; q < 4; ++q)
          lds_acc[hsel][l][m * 16 + n * 4 + q] = acc[m][n][q];
    lds_den[hsel][l][0] = dacc0;
    lds_den[hsel][l][1] = dacc1;
  }
  __syncthreads();
  if (jh == 0) {
#pragma unroll
    for (int m = 0; m < 2; ++m)
#pragma unroll
      for (int n = 0; n < 4; ++n)
#pragma unroll
        for (int q = 0; q < 4; ++q)
          acc[m][n][q] += lds_acc[hsel][l][m * 16 + n * 4 + q];
    dacc0 += lds_den[hsel][l][0];
    dacc1 += lds_den[hsel][l][1];
    // denominator: sum over k-groups (lanes r, r+16, r+32, r+48)
    dacc0 += __shfl_xor(dacc0, 16); dacc0 += __shfl_xor(dacc0, 32);
    dacc1 += __shfl_xor(dacc1, 16); dacc1 += __shfl_xor(dacc1, 32);
    if (l < 16) {
      pden[((size_t)s * NN + i0 + l) * 4 + h] = dacc0;
      pden[((size_t)s * NN + i0 + 16 + l) * 4 + h] = dacc1;
    }
    // C/D: col = l&15, row = 4*(l>>4)+reg
#pragma unroll
    for (int m = 0; m < 2; ++m)
#pragma unroll
      for (int n = 0; n < 4; ++n)
#pragma unroll
        for (int q = 0; q < 4; ++q)
          pacc[((size_t)s * NN + i0 + 16 * m + g * 4 + q) * 256 + h * 64 + n * 16 + r] = acc[m][n][q];
  }
}

// ---------------- k4: combine partials, divide ----------------
__global__ __launch_bounds__(256) void k4_combine(
    const float* __restrict__ pacc, const float* __restrict__ pden,
    float* __restrict__ out)
{
  const int t = threadIdx.x;
  const int i = blockIdx.x * 4 + (t >> 6);
  const int c4 = t & 63;          // float4 column index
  const int h = c4 >> 4;
  const float4* pa = (const float4*)pacc;
  float4 num = {0.f, 0.f, 0.f, 0.f};
  float den = 0.f;
#pragma unroll
  for (int s = 0; s < 4; ++s) {
    float4 v = pa[((size_t)(s * NN + i)) * 64 + c4];
    num.x += v.x; num.y += v.y; num.z += v.z; num.w += v.w;
    den += pden[((size_t)s * NN + i) * 4 + h];
  }
  float inv = 1.f / den;
  float4 o = {num.x * inv, num.y * inv, num.z * inv, num.w * inv};
  ((float4*)out)[(size_t)i * 64 + c4] = o;
}

extern "C" void kernel_launch(void* const* d_in, const int* in_sizes, int n_in,
                              void* d_out, int out_size, void* d_ws, size_t ws_size,
                              hipStream_t stream) {
  const float* hin  = (const float*)d_in[0];
  const int*   adj  = (const int*)d_in[1];
  const float* W    = (const float*)d_in[2];
  const float* bias = (const float*)d_in[3];
  const float* av   = (const float*)d_in[4];
  float* out = (float*)d_out;

  char* ws = (char*)d_ws;
  unsigned short* WhT = (unsigned short*)(ws + 0x0);          // 2 MB
  unsigned short* Whi = (unsigned short*)(ws + 0x200000);     // 128 KB
  unsigned short* Wlo = (unsigned short*)(ws + 0x220000);     // 128 KB
  float* srcv  = (float*)(ws + 0x240000);                     // 64 KB
  float* dstv  = (float*)(ws + 0x250000);                     // 64 KB (SoA [4][NN])
  unsigned* dmaxkey = (unsigned*)(ws + 0x260000);             // 16 B (pad)
  u64* bmask   = (u64*)(ws + 0x261000);                       // 2 MB
  float* pacc  = (float*)(ws + 0x461000);                     // 16 MB
  float* pden  = (float*)(ws + 0x1461000);                    // 256 KB

  k0_prep<<<64, 256, 0, stream>>>(W, Whi, Wlo, dmaxkey);
  k1_mfma<<<1024, 256, 0, stream>>>(hin, Whi, Wlo, bias, av, WhT, srcv, dstv, dmaxkey);
  k2_mask<<<1024, 256, 0, stream>>>(adj, bmask);
  k3_mfma<<<1024, 256, 0, stream>>>(WhT, srcv, dstv, dmaxkey, bmask, pacc, pden);
  k4_combine<<<NN / 4, 256, 0, stream>>>(pacc, pden, out);
}